// Round 12
// baseline (329.096 us; speedup 1.0000x reference)
//
#include <hip/hip_runtime.h>
#include <hip/hip_bf16.h>
#include <math.h>

#define R_CNT   20000
#define L_CNT   30
#define D_CNT   200
#define A_CNT   32
#define B_CNT   4096
#define NNZ_CNT 65536
#define AVG_RATING 3.8f

#define NW 1536           // k_zs: 1536 single-wave blocks (6/CU), 13-14 reviews each

// ---- d_out layout (floats) ----
#define OUT_OBJ  0
#define OUT_RL   1
#define OUT_AB   (1 + B_CNT)               // 4097
#define OUT_PRED (OUT_AB + 2*R_CNT)        // 44097
#define OUT_UA   (OUT_PRED + B_CNT)        // 48193
#define OUT_IA   (OUT_UA + B_CNT*A_CNT)    // 179265

// ---- ws layout (bytes) ----
#define WS_DBL    0         // double[4] (reserved)
#define WS_MODE   32        // int (1 => indices are int64 in memory)
#define WS_FMLIN  64        // float[4096]
#define WS_PT     16448     // float[R*32]
#define WS_V      2576448   // float[R*200]
#define WS_JPART  18627648  // double[NW]
#define WS_SPART  18667648  // double[512]
#define WS_UPART  18671744  // float[32]

// Counted-vmcnt wait: newest N VMEM ops may stay in flight.
#define WAITV(N) do { asm volatile("s_waitcnt vmcnt(" #N ")" ::: "memory"); \
                      __builtin_amdgcn_sched_barrier(0); } while (0)
#define SB0() __builtin_amdgcn_sched_barrier(0)

// Block-wide reduction of 4 channels across 256 threads (4 waves of 64).
__device__ __forceinline__ float4 blk_reduce4(float4 v, float4* scratch) {
    __syncthreads();
    #pragma unroll
    for (int o = 32; o >= 1; o >>= 1) {
        v.x += __shfl_xor(v.x, o);
        v.y += __shfl_xor(v.y, o);
        v.z += __shfl_xor(v.z, o);
        v.w += __shfl_xor(v.w, o);
    }
    int w = threadIdx.x >> 6;
    if ((threadIdx.x & 63) == 0) scratch[w] = v;
    __syncthreads();
    float4 t0 = scratch[0], t1 = scratch[1], t2 = scratch[2], t3 = scratch[3];
    return make_float4(t0.x + t1.x + t2.x + t3.x,
                       t0.y + t1.y + t2.y + t3.y,
                       t0.z + t1.z + t2.z + t3.z,
                       t0.w + t1.w + t2.w + t3.w);
}

// ---- K_pre: role-split fusion of {vgemm | uloss | init} ----
__global__ __launch_bounds__(256) void k_pre(const float* __restrict__ y_s,
                                             const float* __restrict__ M_w,
                                             const float* __restrict__ T_w,
                                             const int* __restrict__ u_idx,
                                             float* __restrict__ V,
                                             float* __restrict__ upart,
                                             float* __restrict__ out,
                                             double* __restrict__ dbl,
                                             int* __restrict__ mode) {
    __shared__ __align__(16) float sh[8224];
    const int tid = threadIdx.x;
    const int bid = blockIdx.x;

    if (bid < 313) {
        float* Msh = sh;             // [25][260]
        float* Ysh = sh + 6500;      // [25][68]
        int r0 = bid * 64;
        int dg = tid & 31, rg = tid >> 5;
        float acc[8][8];
        #pragma unroll
        for (int i = 0; i < 8; i++)
            #pragma unroll
            for (int j = 0; j < 8; j++) acc[i][j] = 0.f;
        for (int e0 = 0; e0 < D_CNT; e0 += 25) {
            __syncthreads();
            for (int idx = tid; idx < 25 * 256; idx += 256) {
                int ee = idx >> 8, d = idx & 255;
                Msh[ee * 260 + d] = (d < D_CNT) ? M_w[(e0 + ee) * D_CNT + d] : 0.f;
            }
            for (int idx = tid; idx < 25 * 64; idx += 256) {
                int rr = idx / 25, ee = idx - rr * 25;
                int row = r0 + rr;
                Ysh[ee * 68 + rr] = (row < R_CNT) ? y_s[row * D_CNT + e0 + ee] : 0.f;
            }
            __syncthreads();
            for (int ee = 0; ee < 25; ee++) {
                const float4 ya = *(const float4*)&Ysh[ee * 68 + rg * 8];
                const float4 yb = *(const float4*)&Ysh[ee * 68 + rg * 8 + 4];
                const float4 ma = *(const float4*)&Msh[ee * 260 + dg * 8];
                const float4 mb = *(const float4*)&Msh[ee * 260 + dg * 8 + 4];
                float ys[8] = {ya.x, ya.y, ya.z, ya.w, yb.x, yb.y, yb.z, yb.w};
                float ms[8] = {ma.x, ma.y, ma.z, ma.w, mb.x, mb.y, mb.z, mb.w};
                #pragma unroll
                for (int i = 0; i < 8; i++)
                    #pragma unroll
                    for (int j = 0; j < 8; j++)
                        acc[i][j] = fmaf(ys[i], ms[j], acc[i][j]);
            }
        }
        if (dg < 25) {
            #pragma unroll
            for (int i = 0; i < 8; i++) {
                int row = r0 + rg * 8 + i;
                if (row < R_CNT) {
                    *(float4*)&V[row * D_CNT + dg * 8]     = make_float4(acc[i][0], acc[i][1], acc[i][2], acc[i][3]);
                    *(float4*)&V[row * D_CNT + dg * 8 + 4] = make_float4(acc[i][4], acc[i][5], acc[i][6], acc[i][7]);
                }
            }
        }
    } else if (bid < 345) {
        float* Tsh = sh;                         // 6400 floats
        float* tn  = sh + 6400;                  // 32
        float4* red4 = (float4*)(sh + 6448);     // 16 floats
        for (int idx = tid; idx < 1600; idx += 256)
            ((float4*)Tsh)[idx] = ((const float4*)T_w)[idx];
        __syncthreads();
        int a = tid >> 3, k = tid & 7;
        float p = 0.f;
        #pragma unroll
        for (int j = 0; j < 25; ++j) { float t = Tsh[(k + 8*j)*32 + a]; p = fmaf(t, t, p); }
        p += __shfl_xor(p, 1); p += __shfl_xor(p, 2); p += __shfl_xor(p, 4);
        if (k == 0) tn[a] = fmaxf(sqrtf(p), 1e-12f);
        __syncthreads();
        const int i = bid - 313;
        float s = 0.f;
        #pragma unroll
        for (int j = 0; j < 25; ++j)
            s = fmaf(Tsh[(k + 8*j)*32 + i], Tsh[(k + 8*j)*32 + a], s);
        s += __shfl_xor(s, 1); s += __shfl_xor(s, 2); s += __shfl_xor(s, 4);
        float part = 0.f;
        if (k == 0) {
            float g = s / (tn[i] * tn[a]);
            float diff = g - ((i == a) ? 1.f : 0.f);
            part = diff * diff;
        }
        float4 tot = blk_reduce4(make_float4(part, 0.f, 0.f, 0.f), red4);
        if (tid == 0) upart[i] = tot.x;
    } else {
        int base = (bid - 345) * 2048;
        #pragma unroll
        for (int j = 0; j < 8; ++j)
            out[OUT_UA + base + j * 256 + tid] = 0.f;
        if (bid == 345 && tid == 0) {
            dbl[0] = 0.0; dbl[1] = 0.0; dbl[2] = 0.0;
            int m = 1;
            for (int i = 1; i < 256; i += 2) if (u_idx[i] != 0) { m = 0; break; }
            *mode = m;
        }
    }
}

// ---- k_zs staging: gload_lds, fixed instruction counts (12 and 4) ----
__device__ __forceinline__ void stage_chunk(const float* src, float* lds,
                                            int lane, const float* ew_last4) {
    #pragma unroll
    for (int i = 0; i < 12; ++i) {
        const float* p = src + i * 256 + lane * 4;
        if (p > ew_last4) p = ew_last4;   // clamp tail (pad LDS slots get dup data)
        __builtin_amdgcn_global_load_lds(
            (const __attribute__((address_space(1))) unsigned int*)p,
            (__attribute__((address_space(3))) unsigned int*)(lds + i * 256),
            16, 0, 0);
    }
}
__device__ __forceinline__ void stage_v(const float* vsrc, float* lds, int lane) {
    #pragma unroll
    for (int i = 0; i < 4; ++i)
        __builtin_amdgcn_global_load_lds(
            (const __attribute__((address_space(1))) unsigned int*)(vsrc + i * 64 + lane),
            (__attribute__((address_space(3))) unsigned int*)(lds + i * 64),
            4, 0, 0);
}

// One half-review chunk (15 rows): dx -> online-softmax merge -> z accum.
__device__ __forceinline__ void chunk_pass(const float* __restrict__ eb,
                                           const float* __restrict__ vb,
                                           float* __restrict__ dxs,
                                           int lane, float& m, float& s,
                                           float4& zacc) {
    int l = lane >> 2, k = lane & 3;
    float p = 0.f;
    if (l < 15) {
        const float4* er = (const float4*)(eb + l * 200);
        const float4* vr = (const float4*)vb;
        #pragma unroll
        for (int t = 0; t < 13; ++t) {
            int idx = k + 4 * t;
            if (idx < 50) {
                float4 e = er[idx], v = vr[idx];
                p += e.x * v.x + e.y * v.y + e.z * v.z + e.w * v.w;
            }
        }
    }
    p += __shfl_xor(p, 1);
    p += __shfl_xor(p, 2);
    if (l < 15 && k == 0) dxs[l] = p;
    float4 d0 = ((const float4*)dxs)[0];
    float4 d1 = ((const float4*)dxs)[1];
    float4 d2 = ((const float4*)dxs)[2];
    float4 d3 = ((const float4*)dxs)[3];
    float dx[15] = {d0.x, d0.y, d0.z, d0.w, d1.x, d1.y, d1.z, d1.w,
                    d2.x, d2.y, d2.z, d2.w, d3.x, d3.y, d3.z};
    float cm = dx[0];
    #pragma unroll
    for (int q = 1; q < 15; ++q) cm = fmaxf(cm, dx[q]);
    float mn = fmaxf(m, cm);
    float sc = __expf(m - mn);
    float w[15];
    float ss = 0.f;
    #pragma unroll
    for (int q = 0; q < 15; ++q) { w[q] = __expf(dx[q] - mn); ss += w[q]; }
    s = s * sc + ss;
    zacc.x *= sc; zacc.y *= sc; zacc.z *= sc; zacc.w *= sc;
    if (lane < 50) {
        #pragma unroll
        for (int q = 0; q < 15; ++q) {
            float4 e = ((const float4*)(eb + q * 200))[lane];
            zacc.x = fmaf(w[q], e.x, zacc.x);
            zacc.y = fmaf(w[q], e.y, zacc.y);
            zacc.z = fmaf(w[q], e.z, zacc.z);
            zacc.w = fmaf(w[q], e.w, zacc.w);
        }
    }
    m = mn;
}

// ---- K_zs: single-wave blocks, zero barriers, double-buffered gload_lds
// pipeline, FUSED tail (p_t + r_s + cosine losses) per review. ----
__global__ __launch_bounds__(64) void k_zs(const float* __restrict__ e_w,
                                           const float* __restrict__ V,
                                           const float* __restrict__ z_n,
                                           const float* __restrict__ W_w,
                                           const float* __restrict__ W_b,
                                           const float* __restrict__ T_w,
                                           const float* __restrict__ T_b,
                                           float* __restrict__ p_t,
                                           float* __restrict__ out,
                                           double* __restrict__ jpart) {
    __shared__ __align__(16) float bufE[2][3072];   // 2 x 12.0KB (+pad)
    __shared__ __align__(16) float bufV[2][256];    // v row + dxs scratch @208
    const int lane = threadIdx.x;
    const bool act = lane < 50;
    const int dl = act ? lane : 0;
    const float* ew_last4 = e_w + (size_t)R_CNT * 6000 - 4;

    // per-kernel constants
    const float wb = W_b[lane >> 1];
    float4 tbv = make_float4(0.f, 0.f, 0.f, 0.f);
    if (act) tbv = ((const float4*)T_b)[dl];
    float tb[4] = {tbv.x, tbv.y, tbv.z, tbv.w};

    double jloc = 0.0;
    int rev = blockIdx.x;
    stage_v(V + (size_t)rev * 200, bufV[0], lane);
    stage_chunk(e_w + (size_t)rev * 6000, bufE[0], lane, ew_last4);   // 16 out
    int pv = 0;
    for (;;) {
        int rnext = rev + NW;
        bool last = (rnext >= R_CNT);
        int rc = last ? rev : rnext;
        float m = -3.0e38f, s = 0.f;
        float4 zacc = make_float4(0.f, 0.f, 0.f, 0.f);
        SB0();
        stage_chunk(e_w + (size_t)rev * 6000 + 3000, bufE[1], lane, ew_last4); // +12
        stage_v(V + (size_t)rc * 200, bufV[pv ^ 1], lane);                     // +4
        float4 zn0 = make_float4(0.f, 0.f, 0.f, 0.f);
        float4 zn1 = make_float4(0.f, 0.f, 0.f, 0.f);
        if (act) {                                                             // +2
            zn0 = ((const float4*)(z_n + (size_t)(2 * rev) * 200))[lane];
            zn1 = ((const float4*)(z_n + (size_t)(2 * rev + 1) * 200))[lane];
        }
        WAITV(18);   // chunkA + v(rev) landed (also drains prev tail stores)
        chunk_pass(bufE[0], bufV[pv], bufV[pv] + 208, lane, m, s, zacc);
        SB0();
        stage_chunk(e_w + (size_t)rc * 6000, bufE[0], lane, ew_last4);         // +12
        WAITV(18);   // chunkB landed; v(next)+zn+chunkA(next) stay in flight
        chunk_pass(bufE[1], bufV[pv], bufV[pv] + 208, lane, m, s, zacc);

        // ---- fused tail (wave-synchronous; bufE[1] reused as scratch) ----
        float* zsh  = bufE[1];         // 200 floats: z_s
        float* ptsL = bufE[1] + 208;   // 32 floats: p_t (16B aligned)
        const float inv = 1.f / s;
        float zf[4] = {zacc.x * inv, zacc.y * inv, zacc.z * inv, zacc.w * inv};
        if (act) ((float4*)zsh)[dl] = make_float4(zf[0], zf[1], zf[2], zf[3]);

        {   // p_t: 2 lanes per aspect
            int a = lane >> 1, half = lane & 1;
            const float4* wrow = (const float4*)(W_w + a * 200);
            const float4* zrow = (const float4*)zsh;
            float p = 0.f;
            #pragma unroll
            for (int t = 0; t < 25; ++t) {
                int idx = half + 2 * t;
                float4 wv = wrow[idx];
                float4 zv = zrow[idx];
                p += wv.x * zv.x + wv.y * zv.y + wv.z * zv.z + wv.w * zv.w;
            }
            p += __shfl_xor(p, 1);
            float pt = p + wb;
            if (half == 0) {
                ptsL[a] = pt;
                p_t[(size_t)rev * 32 + a] = pt;                                 // store
            }
        }

        // r_s per-lane-d + 7-channel loss partials
        float rr = 0.f, rz = 0.f, zz = 0.f, n00 = 0.f, n0r = 0.f, n11 = 0.f, n1r = 0.f;
        {
            const float4* pt4 = (const float4*)ptsL;
            float4 pq0 = pt4[0], pq1 = pt4[1], pq2 = pt4[2], pq3 = pt4[3];
            float4 pq4 = pt4[4], pq5 = pt4[5], pq6 = pt4[6], pq7 = pt4[7];
            if (act) {
                float znf0[4] = {zn0.x, zn0.y, zn0.z, zn0.w};
                float znf1[4] = {zn1.x, zn1.y, zn1.z, zn1.w};
                #pragma unroll
                for (int j = 0; j < 4; ++j) {
                    int d = 4 * dl + j;
                    const float4* trow = (const float4*)(T_w + d * 32);
                    float r = tb[j];
                    float4 t0 = trow[0], t1 = trow[1], t2 = trow[2], t3 = trow[3];
                    float4 t4 = trow[4], t5 = trow[5], t6 = trow[6], t7 = trow[7];
                    r += t0.x*pq0.x + t0.y*pq0.y + t0.z*pq0.z + t0.w*pq0.w;
                    r += t1.x*pq1.x + t1.y*pq1.y + t1.z*pq1.z + t1.w*pq1.w;
                    r += t2.x*pq2.x + t2.y*pq2.y + t2.z*pq2.z + t2.w*pq2.w;
                    r += t3.x*pq3.x + t3.y*pq3.y + t3.z*pq3.z + t3.w*pq3.w;
                    r += t4.x*pq4.x + t4.y*pq4.y + t4.z*pq4.z + t4.w*pq4.w;
                    r += t5.x*pq5.x + t5.y*pq5.y + t5.z*pq5.z + t5.w*pq5.w;
                    r += t6.x*pq6.x + t6.y*pq6.y + t6.z*pq6.z + t6.w*pq6.w;
                    r += t7.x*pq7.x + t7.y*pq7.y + t7.z*pq7.z + t7.w*pq7.w;
                    rr  += r * r;
                    rz  += r * zf[j];
                    zz  += zf[j] * zf[j];
                    n00 += znf0[j] * znf0[j];
                    n0r += znf0[j] * r;
                    n11 += znf1[j] * znf1[j];
                    n1r += znf1[j] * r;
                }
            }
        }
        #pragma unroll
        for (int o = 1; o < 64; o <<= 1) {
            rr  += __shfl_xor(rr, o);  rz  += __shfl_xor(rz, o);
            zz  += __shfl_xor(zz, o);  n00 += __shfl_xor(n00, o);
            n0r += __shfl_xor(n0r, o); n11 += __shfl_xor(n11, o);
            n1r += __shfl_xor(n1r, o);
        }
        if (lane == 0) {
            float nr = fmaxf(sqrtf(rr), 1e-12f);
            float nz = fmaxf(sqrtf(zz), 1e-12f);
            float c1  = rz  / (nr * nz);
            float c20 = n0r / (fmaxf(sqrtf(n00), 1e-12f) * nr);
            float c21 = n1r / (fmaxf(sqrtf(n11), 1e-12f) * nr);
            float l0 = fmaxf(0.f, 1.f - (c1 - c20));
            float l1 = fmaxf(0.f, 1.f - (c1 - c21));
            out[OUT_AB + 2 * rev]     = l0;                                     // store
            out[OUT_AB + 2 * rev + 1] = l1;                                     // store
            jloc += (double)l0 + (double)l1;
        }
        if (last) break;
        rev = rnext;
        pv ^= 1;
    }
    if (lane == 0) jpart[blockIdx.x] = jloc;
}

// ---- K_scatter: user/item aspect segment sums via atomics ----
__global__ __launch_bounds__(256) void k_scatter(const int* __restrict__ u_idx,
                                                 const int* __restrict__ i_idx,
                                                 const float* __restrict__ u_val,
                                                 const float* __restrict__ i_val,
                                                 const float* __restrict__ p_t,
                                                 const int* __restrict__ mode,
                                                 float* __restrict__ out) {
    long long gid = (long long)blockIdx.x * 256 + threadIdx.x;
    const long long HALF = (long long)NNZ_CNT * 32;
    int is_item = gid >= HALF;
    long long rem = gid - (is_item ? HALF : 0);
    int k = (int)(rem >> 5), a = (int)(rem & 31);
    const int* idx = is_item ? i_idx : u_idx;
    const float* val = is_item ? i_val : u_val;
    int m64 = *mode;
    int row, col;
    if (m64) { row = idx[2 * k]; col = idx[2 * (NNZ_CNT + k)]; }
    else     { row = idx[k];     col = idx[NNZ_CNT + k]; }
    float v = p_t[col * 32 + a] * val[k];
    float* base = out + (is_item ? OUT_IA : OUT_UA);
    atomicAdd(&base[row * 32 + a], v);
}

// ---- K_fm: FM per-b terms; per-block partial of the global scalar S ----
__global__ __launch_bounds__(256) void k_fm(const float* __restrict__ out,
                                            const float* __restrict__ fc_w,
                                            const float* __restrict__ fc_b,
                                            const float* __restrict__ fm_V,
                                            float* __restrict__ fm_lin,
                                            double* __restrict__ spart) {
    __shared__ float parts[8];
    int tid = threadIdx.x;
    int a = tid & 31;
    int b = blockIdx.x * 8 + (tid >> 5);
    float ua = out[OUT_UA + b * 32 + a];
    float ia = out[OUT_IA + b * 32 + a];
    float oe = ua * ia;
    float oe2 = oe * oe;
    float lin = oe * fc_w[a];
    #pragma unroll
    for (int o = 1; o < 32; o <<= 1) lin += __shfl_xor(lin, o);
    float part = 0.f;
    #pragma unroll
    for (int j = 0; j < 10; j++) {
        float v = fm_V[a * 10 + j];
        float s1 = oe * v;
        float s2 = oe2 * v * v;
        #pragma unroll
        for (int o = 1; o < 32; o <<= 1) { s1 += __shfl_xor(s1, o); s2 += __shfl_xor(s2, o); }
        part += s1 * s1 - s2;
    }
    if (a == 0) {
        fm_lin[b] = lin + fc_b[0];
        parts[tid >> 5] = part;
    }
    __syncthreads();
    if (tid == 0) {
        float s = 0.f;
        #pragma unroll
        for (int i = 0; i < 8; ++i) s += parts[i];
        spart[blockIdx.x] = 0.5 * (double)s;
    }
}

// ---- K_predfinal: single block — S reduce, preds, rating loss, objective ----
__global__ __launch_bounds__(256) void k_predfinal(const float* __restrict__ label,
                                                   const float* __restrict__ fm_lin,
                                                   const double* __restrict__ spart,
                                                   const double* __restrict__ jpart,
                                                   const float* __restrict__ upart,
                                                   float* __restrict__ out) {
    __shared__ double dred[4];
    __shared__ float Ssh;
    __shared__ float ured[4];
    int tid = threadIdx.x;
    double sl = spart[tid] + spart[tid + 256];
    #pragma unroll
    for (int o = 32; o >= 1; o >>= 1) sl += __shfl_xor(sl, o);
    if ((tid & 63) == 0) dred[tid >> 6] = sl;
    __syncthreads();
    if (tid == 0) Ssh = (float)(dred[0] + dred[1] + dred[2] + dred[3]);
    __syncthreads();
    float S = Ssh;
    double racc = 0.0;
    #pragma unroll
    for (int i = 0; i < 16; ++i) {
        int b = tid + 256 * i;
        float pred = fm_lin[b] + S + AVG_RATING;
        float d = pred - label[b];
        float rl = d * d;
        out[OUT_PRED + b] = pred;
        out[OUT_RL + b] = rl;
        racc += (double)rl;
    }
    double jacc = 0.0;
    for (int i = tid; i < NW; i += 256) jacc += jpart[i];
    float u = (tid < 32) ? upart[tid] : 0.f;
    #pragma unroll
    for (int o = 32; o >= 1; o >>= 1) {
        racc += __shfl_xor(racc, o);
        jacc += __shfl_xor(jacc, o);
        u    += __shfl_xor(u, o);
    }
    __syncthreads();
    if ((tid & 63) == 0) dred[tid >> 6] = racc;
    __syncthreads();
    double rsum = dred[0] + dred[1] + dred[2] + dred[3];
    __syncthreads();
    if ((tid & 63) == 0) dred[tid >> 6] = jacc;
    __syncthreads();
    double jsum = dred[0] + dred[1] + dred[2] + dred[3];
    if ((tid & 63) == 0) ured[tid >> 6] = u;
    __syncthreads();
    if (tid == 0) {
        double U = (double)(ured[0] + ured[1] + ured[2] + ured[3]) / 1024.0;
        double J = jsum / (2.0 * R_CNT);
        double RL = rsum / (double)B_CNT;
        out[OUT_OBJ] = (float)(RL + U + J);
    }
}

extern "C" void kernel_launch(void* const* d_in, const int* in_sizes, int n_in,
                              void* d_out, int out_size, void* d_ws, size_t ws_size,
                              hipStream_t stream) {
    const float* e_w   = (const float*)d_in[0];
    const float* y_s   = (const float*)d_in[1];
    const float* z_n   = (const float*)d_in[2];
    const float* label = (const float*)d_in[3];
    const float* u_val = (const float*)d_in[4];
    const float* i_val = (const float*)d_in[5];
    const float* M_w   = (const float*)d_in[6];
    const float* W_w   = (const float*)d_in[8];
    const float* W_b   = (const float*)d_in[9];
    const float* T_w   = (const float*)d_in[10];
    const float* T_b   = (const float*)d_in[11];
    const float* fc_w  = (const float*)d_in[12];
    const float* fc_b  = (const float*)d_in[13];
    const float* fm_V  = (const float*)d_in[14];
    const int*   u_idx = (const int*)d_in[15];
    const int*   i_idx = (const int*)d_in[16];

    float* out = (float*)d_out;
    char* ws = (char*)d_ws;
    double* dbl   = (double*)(ws + WS_DBL);
    int* mode     = (int*)(ws + WS_MODE);
    float* fm_lin = (float*)(ws + WS_FMLIN);
    float* p_t    = (float*)(ws + WS_PT);
    float* V      = (float*)(ws + WS_V);
    double* jpart = (double*)(ws + WS_JPART);
    double* spart = (double*)(ws + WS_SPART);
    float* upart  = (float*)(ws + WS_UPART);

    k_pre<<<473, 256, 0, stream>>>(y_s, M_w, T_w, u_idx, V, upart, out, dbl, mode);
    k_zs<<<NW, 64, 0, stream>>>(e_w, V, z_n, W_w, W_b, T_w, T_b, p_t, out, jpart);
    k_scatter<<<(2 * NNZ_CNT * 32) / 256, 256, 0, stream>>>(u_idx, i_idx, u_val, i_val,
                                                            p_t, mode, out);
    k_fm<<<B_CNT / 8, 256, 0, stream>>>(out, fc_w, fc_b, fm_V, fm_lin, spart);
    k_predfinal<<<1, 256, 0, stream>>>(label, fm_lin, spart, jpart, upart, out);
}

// Round 13
// 327.265 us; speedup vs baseline: 1.0056x; 1.0056x over previous
//
#include <hip/hip_runtime.h>
#include <hip/hip_bf16.h>
#include <math.h>

#define R_CNT   20000
#define L_CNT   30
#define D_CNT   200
#define A_CNT   32
#define B_CNT   4096
#define NNZ_CNT 65536
#define AVG_RATING 3.8f

#define NW 1536           // k_zs: 1536 single-wave blocks (6/CU), 13-14 reviews each
#define BUCK_CAP 128      // bucket capacity per (side,row); Poisson(16) -> safe

// ---- d_out layout (floats) ----
#define OUT_OBJ  0
#define OUT_RL   1
#define OUT_AB   (1 + B_CNT)               // 4097
#define OUT_PRED (OUT_AB + 2*R_CNT)        // 44097
#define OUT_UA   (OUT_PRED + B_CNT)        // 48193
#define OUT_IA   (OUT_UA + B_CNT*A_CNT)    // 179265

// ---- ws layout (bytes) ----
#define WS_MODE   32        // int (1 => indices are int64 in memory)
#define WS_FMLIN  64        // float[4096]
#define WS_PT     16448     // float[R*32]
#define WS_V      2576448   // float[R*200]
#define WS_JPART  18576448  // double[NW]
#define WS_SFPART 18588736  // float[4096]
#define WS_UPART  18605120  // float[32]
#define WS_CNT    18605248  // int[8192]
#define WS_BUCK   18638016  // long long[8192*128] = 8MB

// Counted-vmcnt wait: newest N VMEM ops may stay in flight.
#define WAITV(N) do { asm volatile("s_waitcnt vmcnt(" #N ")" ::: "memory"); \
                      __builtin_amdgcn_sched_barrier(0); } while (0)
#define SB0() __builtin_amdgcn_sched_barrier(0)
#define WAIT_ALL() do { asm volatile("s_waitcnt vmcnt(0) lgkmcnt(0)" ::: "memory"); \
                        __builtin_amdgcn_sched_barrier(0); } while (0)

// Block-wide reduction of 4 channels across 256 threads (4 waves of 64).
__device__ __forceinline__ float4 blk_reduce4(float4 v, float4* scratch) {
    __syncthreads();
    #pragma unroll
    for (int o = 32; o >= 1; o >>= 1) {
        v.x += __shfl_xor(v.x, o);
        v.y += __shfl_xor(v.y, o);
        v.z += __shfl_xor(v.z, o);
        v.w += __shfl_xor(v.w, o);
    }
    int w = threadIdx.x >> 6;
    if ((threadIdx.x & 63) == 0) scratch[w] = v;
    __syncthreads();
    float4 t0 = scratch[0], t1 = scratch[1], t2 = scratch[2], t3 = scratch[3];
    return make_float4(t0.x + t1.x + t2.x + t3.x,
                       t0.y + t1.y + t2.y + t3.y,
                       t0.z + t1.z + t2.z + t3.z,
                       t0.w + t1.w + t2.w + t3.w);
}

// ---- K_pre: role-split fusion of {vgemm | uloss | init} ----
// blocks [0,313): V = y_s @ M_w (64 rows each)
// blocks [313,345): uloss G-row per block
// block 345: zero cnt[8192], detect index dtype
__global__ __launch_bounds__(256) void k_pre(const float* __restrict__ y_s,
                                             const float* __restrict__ M_w,
                                             const float* __restrict__ T_w,
                                             const int* __restrict__ u_idx,
                                             float* __restrict__ V,
                                             float* __restrict__ upart,
                                             int* __restrict__ cnt,
                                             int* __restrict__ mode) {
    __shared__ __align__(16) float sh[8224];
    const int tid = threadIdx.x;
    const int bid = blockIdx.x;

    if (bid < 313) {
        float* Msh = sh;             // [25][260]
        float* Ysh = sh + 6500;      // [25][68]
        int r0 = bid * 64;
        int dg = tid & 31, rg = tid >> 5;
        float acc[8][8];
        #pragma unroll
        for (int i = 0; i < 8; i++)
            #pragma unroll
            for (int j = 0; j < 8; j++) acc[i][j] = 0.f;
        for (int e0 = 0; e0 < D_CNT; e0 += 25) {
            __syncthreads();
            for (int idx = tid; idx < 25 * 256; idx += 256) {
                int ee = idx >> 8, d = idx & 255;
                Msh[ee * 260 + d] = (d < D_CNT) ? M_w[(e0 + ee) * D_CNT + d] : 0.f;
            }
            for (int idx = tid; idx < 25 * 64; idx += 256) {
                int rr = idx / 25, ee = idx - rr * 25;
                int row = r0 + rr;
                Ysh[ee * 68 + rr] = (row < R_CNT) ? y_s[row * D_CNT + e0 + ee] : 0.f;
            }
            __syncthreads();
            for (int ee = 0; ee < 25; ee++) {
                const float4 ya = *(const float4*)&Ysh[ee * 68 + rg * 8];
                const float4 yb = *(const float4*)&Ysh[ee * 68 + rg * 8 + 4];
                const float4 ma = *(const float4*)&Msh[ee * 260 + dg * 8];
                const float4 mb = *(const float4*)&Msh[ee * 260 + dg * 8 + 4];
                float ys[8] = {ya.x, ya.y, ya.z, ya.w, yb.x, yb.y, yb.z, yb.w};
                float ms[8] = {ma.x, ma.y, ma.z, ma.w, mb.x, mb.y, mb.z, mb.w};
                #pragma unroll
                for (int i = 0; i < 8; i++)
                    #pragma unroll
                    for (int j = 0; j < 8; j++)
                        acc[i][j] = fmaf(ys[i], ms[j], acc[i][j]);
            }
        }
        if (dg < 25) {
            #pragma unroll
            for (int i = 0; i < 8; i++) {
                int row = r0 + rg * 8 + i;
                if (row < R_CNT) {
                    *(float4*)&V[row * D_CNT + dg * 8]     = make_float4(acc[i][0], acc[i][1], acc[i][2], acc[i][3]);
                    *(float4*)&V[row * D_CNT + dg * 8 + 4] = make_float4(acc[i][4], acc[i][5], acc[i][6], acc[i][7]);
                }
            }
        }
    } else if (bid < 345) {
        float* Tsh = sh;                         // 6400 floats
        float* tn  = sh + 6400;                  // 32
        float4* red4 = (float4*)(sh + 6448);     // 16 floats
        for (int idx = tid; idx < 1600; idx += 256)
            ((float4*)Tsh)[idx] = ((const float4*)T_w)[idx];
        __syncthreads();
        int a = tid >> 3, k = tid & 7;
        float p = 0.f;
        #pragma unroll
        for (int j = 0; j < 25; ++j) { float t = Tsh[(k + 8*j)*32 + a]; p = fmaf(t, t, p); }
        p += __shfl_xor(p, 1); p += __shfl_xor(p, 2); p += __shfl_xor(p, 4);
        if (k == 0) tn[a] = fmaxf(sqrtf(p), 1e-12f);
        __syncthreads();
        const int i = bid - 313;
        float s = 0.f;
        #pragma unroll
        for (int j = 0; j < 25; ++j)
            s = fmaf(Tsh[(k + 8*j)*32 + i], Tsh[(k + 8*j)*32 + a], s);
        s += __shfl_xor(s, 1); s += __shfl_xor(s, 2); s += __shfl_xor(s, 4);
        float part = 0.f;
        if (k == 0) {
            float g = s / (tn[i] * tn[a]);
            float diff = g - ((i == a) ? 1.f : 0.f);
            part = diff * diff;
        }
        float4 tot = blk_reduce4(make_float4(part, 0.f, 0.f, 0.f), red4);
        if (tid == 0) upart[i] = tot.x;
    } else {
        #pragma unroll
        for (int j = 0; j < 32; ++j) cnt[j * 256 + tid] = 0;
        if (tid == 0) {
            int m = 1;
            for (int i = 1; i < 256; i += 2) if (u_idx[i] != 0) { m = 0; break; }
            *mode = m;
        }
    }
}

// ---- K_bucket: scatter (col,val) into per-(side,row) buckets; int atomics only ----
__global__ __launch_bounds__(256) void k_bucket(const int* __restrict__ u_idx,
                                                const int* __restrict__ i_idx,
                                                const float* __restrict__ u_val,
                                                const float* __restrict__ i_val,
                                                const int* __restrict__ mode,
                                                int* __restrict__ cnt,
                                                long long* __restrict__ buck) {
    int gid = blockIdx.x * 256 + threadIdx.x;      // 0 .. 2*NNZ-1
    int side = gid >= NNZ_CNT;
    int k = gid - (side ? NNZ_CNT : 0);
    const int* idx = side ? i_idx : u_idx;
    float val = (side ? i_val : u_val)[k];
    int m64 = *mode;
    int row, col;
    if (m64) { row = idx[2 * k]; col = idx[2 * (NNZ_CNT + k)]; }
    else     { row = idx[k];     col = idx[NNZ_CNT + k]; }
    int bin = side * B_CNT + row;
    int slot = atomicAdd(&cnt[bin], 1);
    if (slot < BUCK_CAP) {
        long long pk = (long long)(unsigned int)col |
                       ((long long)__float_as_int(val) << 32);
        buck[(size_t)bin * BUCK_CAP + slot] = pk;
    }
}

// ---- k_zs staging: gload_lds, fixed instruction counts (12 and 4) ----
__device__ __forceinline__ void stage_chunk(const float* src, float* lds,
                                            int lane, const float* ew_last4) {
    #pragma unroll
    for (int i = 0; i < 12; ++i) {
        const float* p = src + i * 256 + lane * 4;
        if (p > ew_last4) p = ew_last4;   // clamp tail (pad LDS slots get dup data)
        __builtin_amdgcn_global_load_lds(
            (const __attribute__((address_space(1))) unsigned int*)p,
            (__attribute__((address_space(3))) unsigned int*)(lds + i * 256),
            16, 0, 0);
    }
}
__device__ __forceinline__ void stage_v(const float* vsrc, float* lds, int lane) {
    #pragma unroll
    for (int i = 0; i < 4; ++i)
        __builtin_amdgcn_global_load_lds(
            (const __attribute__((address_space(1))) unsigned int*)(vsrc + i * 64 + lane),
            (__attribute__((address_space(3))) unsigned int*)(lds + i * 64),
            4, 0, 0);
}

// One half-review chunk (15 rows): dx -> online-softmax merge -> z accum.
__device__ __forceinline__ void chunk_pass(const float* __restrict__ eb,
                                           const float* __restrict__ vb,
                                           float* __restrict__ dxs,
                                           int lane, float& m, float& s,
                                           float4& zacc) {
    int l = lane >> 2, k = lane & 3;
    float p = 0.f;
    if (l < 15) {
        const float4* er = (const float4*)(eb + l * 200);
        const float4* vr = (const float4*)vb;
        #pragma unroll
        for (int t = 0; t < 13; ++t) {
            int idx = k + 4 * t;
            if (idx < 50) {
                float4 e = er[idx], v = vr[idx];
                p += e.x * v.x + e.y * v.y + e.z * v.z + e.w * v.w;
            }
        }
    }
    p += __shfl_xor(p, 1);
    p += __shfl_xor(p, 2);
    if (l < 15 && k == 0) dxs[l] = p;
    float4 d0 = ((const float4*)dxs)[0];
    float4 d1 = ((const float4*)dxs)[1];
    float4 d2 = ((const float4*)dxs)[2];
    float4 d3 = ((const float4*)dxs)[3];
    float dx[15] = {d0.x, d0.y, d0.z, d0.w, d1.x, d1.y, d1.z, d1.w,
                    d2.x, d2.y, d2.z, d2.w, d3.x, d3.y, d3.z};
    float cm = dx[0];
    #pragma unroll
    for (int q = 1; q < 15; ++q) cm = fmaxf(cm, dx[q]);
    float mn = fmaxf(m, cm);
    float sc = __expf(m - mn);
    float w[15];
    float ss = 0.f;
    #pragma unroll
    for (int q = 0; q < 15; ++q) { w[q] = __expf(dx[q] - mn); ss += w[q]; }
    s = s * sc + ss;
    zacc.x *= sc; zacc.y *= sc; zacc.z *= sc; zacc.w *= sc;
    if (lane < 50) {
        #pragma unroll
        for (int q = 0; q < 15; ++q) {
            float4 e = ((const float4*)(eb + q * 200))[lane];
            zacc.x = fmaf(w[q], e.x, zacc.x);
            zacc.y = fmaf(w[q], e.y, zacc.y);
            zacc.z = fmaf(w[q], e.z, zacc.z);
            zacc.w = fmaf(w[q], e.w, zacc.w);
        }
    }
    m = mn;
}

// ---- K_zs: single-wave blocks, zero barriers, double-buffered gload_lds
// pipeline, fused tail (p_t + r_s + cosine losses) per review. ----
__global__ __launch_bounds__(64) void k_zs(const float* __restrict__ e_w,
                                           const float* __restrict__ V,
                                           const float* __restrict__ z_n,
                                           const float* __restrict__ W_w,
                                           const float* __restrict__ W_b,
                                           const float* __restrict__ T_w,
                                           const float* __restrict__ T_b,
                                           float* __restrict__ p_t,
                                           float* __restrict__ out,
                                           double* __restrict__ jpart) {
    __shared__ __align__(16) float bufE[2][3072];   // 2 x 12.0KB (+pad)
    __shared__ __align__(16) float bufV[2][256];    // v row + dxs scratch @208
    const int lane = threadIdx.x;
    const bool act = lane < 50;
    const int dl = act ? lane : 0;
    const float* ew_last4 = e_w + (size_t)R_CNT * 6000 - 4;

    const float wb = W_b[lane >> 1];
    float4 tbv = make_float4(0.f, 0.f, 0.f, 0.f);
    if (act) tbv = ((const float4*)T_b)[dl];
    float tb[4] = {tbv.x, tbv.y, tbv.z, tbv.w};

    double jloc = 0.0;
    int rev = blockIdx.x;
    stage_v(V + (size_t)rev * 200, bufV[0], lane);
    stage_chunk(e_w + (size_t)rev * 6000, bufE[0], lane, ew_last4);   // 16 out
    int pv = 0;
    for (;;) {
        int rnext = rev + NW;
        bool last = (rnext >= R_CNT);
        int rc = last ? rev : rnext;
        float m = -3.0e38f, s = 0.f;
        float4 zacc = make_float4(0.f, 0.f, 0.f, 0.f);
        SB0();
        stage_chunk(e_w + (size_t)rev * 6000 + 3000, bufE[1], lane, ew_last4); // +12
        stage_v(V + (size_t)rc * 200, bufV[pv ^ 1], lane);                     // +4
        float4 zn0 = make_float4(0.f, 0.f, 0.f, 0.f);
        float4 zn1 = make_float4(0.f, 0.f, 0.f, 0.f);
        if (act) {                                                             // +2
            zn0 = ((const float4*)(z_n + (size_t)(2 * rev) * 200))[lane];
            zn1 = ((const float4*)(z_n + (size_t)(2 * rev + 1) * 200))[lane];
        }
        WAITV(18);   // chunkA + v(rev) landed
        chunk_pass(bufE[0], bufV[pv], bufV[pv] + 208, lane, m, s, zacc);
        SB0();
        stage_chunk(e_w + (size_t)rc * 6000, bufE[0], lane, ew_last4);         // +12
        WAITV(18);   // chunkB landed; v(next)+zn+chunkA(next) stay in flight
        chunk_pass(bufE[1], bufV[pv], bufV[pv] + 208, lane, m, s, zacc);

        // ---- fused tail (wave-synchronous; bufE[1] reused as scratch) ----
        float* zsh  = bufE[1];         // 200 floats: z_s
        float* ptsL = bufE[1] + 208;   // 32 floats: p_t (16B aligned)
        const float inv = 1.f / s;
        float zf[4] = {zacc.x * inv, zacc.y * inv, zacc.z * inv, zacc.w * inv};
        if (act) ((float4*)zsh)[dl] = make_float4(zf[0], zf[1], zf[2], zf[3]);

        {   // p_t: 2 lanes per aspect
            int a = lane >> 1, half = lane & 1;
            const float4* wrow = (const float4*)(W_w + a * 200);
            const float4* zrow = (const float4*)zsh;
            float p = 0.f;
            #pragma unroll
            for (int t = 0; t < 25; ++t) {
                int idx = half + 2 * t;
                float4 wv = wrow[idx];
                float4 zv = zrow[idx];
                p += wv.x * zv.x + wv.y * zv.y + wv.z * zv.z + wv.w * zv.w;
            }
            p += __shfl_xor(p, 1);
            float pt = p + wb;
            if (half == 0) {
                ptsL[a] = pt;
                p_t[(size_t)rev * 32 + a] = pt;
            }
        }

        // r_s per-lane-d + 7-channel loss partials
        float rr = 0.f, rz = 0.f, zz = 0.f, n00 = 0.f, n0r = 0.f, n11 = 0.f, n1r = 0.f;
        {
            const float4* pt4 = (const float4*)ptsL;
            float4 pq0 = pt4[0], pq1 = pt4[1], pq2 = pt4[2], pq3 = pt4[3];
            float4 pq4 = pt4[4], pq5 = pt4[5], pq6 = pt4[6], pq7 = pt4[7];
            if (act) {
                float znf0[4] = {zn0.x, zn0.y, zn0.z, zn0.w};
                float znf1[4] = {zn1.x, zn1.y, zn1.z, zn1.w};
                #pragma unroll
                for (int j = 0; j < 4; ++j) {
                    int d = 4 * dl + j;
                    const float4* trow = (const float4*)(T_w + d * 32);
                    float r = tb[j];
                    float4 t0 = trow[0], t1 = trow[1], t2 = trow[2], t3 = trow[3];
                    float4 t4 = trow[4], t5 = trow[5], t6 = trow[6], t7 = trow[7];
                    r += t0.x*pq0.x + t0.y*pq0.y + t0.z*pq0.z + t0.w*pq0.w;
                    r += t1.x*pq1.x + t1.y*pq1.y + t1.z*pq1.z + t1.w*pq1.w;
                    r += t2.x*pq2.x + t2.y*pq2.y + t2.z*pq2.z + t2.w*pq2.w;
                    r += t3.x*pq3.x + t3.y*pq3.y + t3.z*pq3.z + t3.w*pq3.w;
                    r += t4.x*pq4.x + t4.y*pq4.y + t4.z*pq4.z + t4.w*pq4.w;
                    r += t5.x*pq5.x + t5.y*pq5.y + t5.z*pq5.z + t5.w*pq5.w;
                    r += t6.x*pq6.x + t6.y*pq6.y + t6.z*pq6.z + t6.w*pq6.w;
                    r += t7.x*pq7.x + t7.y*pq7.y + t7.z*pq7.z + t7.w*pq7.w;
                    rr  += r * r;
                    rz  += r * zf[j];
                    zz  += zf[j] * zf[j];
                    n00 += znf0[j] * znf0[j];
                    n0r += znf0[j] * r;
                    n11 += znf1[j] * znf1[j];
                    n1r += znf1[j] * r;
                }
            }
        }
        #pragma unroll
        for (int o = 1; o < 64; o <<= 1) {
            rr  += __shfl_xor(rr, o);  rz  += __shfl_xor(rz, o);
            zz  += __shfl_xor(zz, o);  n00 += __shfl_xor(n00, o);
            n0r += __shfl_xor(n0r, o); n11 += __shfl_xor(n11, o);
            n1r += __shfl_xor(n1r, o);
        }
        if (lane == 0) {
            float nr = fmaxf(sqrtf(rr), 1e-12f);
            float nz = fmaxf(sqrtf(zz), 1e-12f);
            float c1  = rz  / (nr * nz);
            float c20 = n0r / (fmaxf(sqrtf(n00), 1e-12f) * nr);
            float c21 = n1r / (fmaxf(sqrtf(n11), 1e-12f) * nr);
            float l0 = fmaxf(0.f, 1.f - (c1 - c20));
            float l1 = fmaxf(0.f, 1.f - (c1 - c21));
            out[OUT_AB + 2 * rev]     = l0;
            out[OUT_AB + 2 * rev + 1] = l1;
            jloc += (double)l0 + (double)l1;
        }
        if (last) break;
        rev = rnext;
        pv ^= 1;
    }
    if (lane == 0) jpart[blockIdx.x] = jloc;
}

// ---- K_rowsum_fm: one wave per output row b. Gather buckets -> UA/IA rows
// (atomic-free, written once) + fused factorization machine. ----
__global__ __launch_bounds__(64) void k_rowsum_fm(const long long* __restrict__ buck,
                                                  const int* __restrict__ cnt,
                                                  const float* __restrict__ p_t,
                                                  const float* __restrict__ fc_w,
                                                  const float* __restrict__ fc_b,
                                                  const float* __restrict__ fm_V,
                                                  float* __restrict__ fm_lin,
                                                  float* __restrict__ sfpart,
                                                  float* __restrict__ out) {
    __shared__ long long ent[2][BUCK_CAP];
    const int lane = threadIdx.x;
    const int b = blockIdx.x;
    const int a = lane & 31;

    int n0 = cnt[b];          if (n0 > BUCK_CAP) n0 = BUCK_CAP;
    int n1 = cnt[B_CNT + b];  if (n1 > BUCK_CAP) n1 = BUCK_CAP;
    {
        const long long* s0 = buck + (size_t)b * BUCK_CAP;
        const long long* s1 = buck + (size_t)(B_CNT + b) * BUCK_CAP;
        if (lane < n0)      ent[0][lane]      = s0[lane];
        if (lane + 64 < n0) ent[0][lane + 64] = s0[lane + 64];
        if (lane < n1)      ent[1][lane]      = s1[lane];
        if (lane + 64 < n1) ent[1][lane + 64] = s1[lane + 64];
    }
    WAIT_ALL();   // single wave: LDS writes visible after drain, no barrier needed

    float side_acc[2];
    const int h = lane >> 5;   // halves process even/odd entries
    #pragma unroll
    for (int s = 0; s < 2; ++s) {
        int n = s ? n1 : n0;
        float acc = 0.f;
        for (int e = h; e < n; e += 2) {
            long long pk = ent[s][e];
            int col = (int)(unsigned int)(pk & 0xffffffffLL);
            float val = __int_as_float((int)(pk >> 32));
            acc = fmaf(p_t[(size_t)col * 32 + a], val, acc);
        }
        acc += __shfl_xor(acc, 32);   // combine halves; all 64 lanes hold sum(a)
        side_acc[s] = acc;
        if (lane < 32)
            out[(s ? OUT_IA : OUT_UA) + b * 32 + lane] = acc;
    }

    // fused FM for this b
    float oe = side_acc[0] * side_acc[1];
    float oe2 = oe * oe;
    float lin = oe * fc_w[a];
    #pragma unroll
    for (int o = 1; o < 32; o <<= 1) lin += __shfl_xor(lin, o);
    float part = 0.f;
    #pragma unroll
    for (int j = 0; j < 10; ++j) {
        float v = fm_V[a * 10 + j];
        float s1 = oe * v;
        float s2 = oe2 * v * v;
        #pragma unroll
        for (int o = 1; o < 32; o <<= 1) { s1 += __shfl_xor(s1, o); s2 += __shfl_xor(s2, o); }
        part += s1 * s1 - s2;
    }
    if (lane == 0) {
        fm_lin[b] = lin + fc_b[0];
        sfpart[b] = 0.5f * part;
    }
}

// ---- K_predfinal: single block — S reduce, preds, rating loss, objective ----
__global__ __launch_bounds__(256) void k_predfinal(const float* __restrict__ label,
                                                   const float* __restrict__ fm_lin,
                                                   const float* __restrict__ sfpart,
                                                   const double* __restrict__ jpart,
                                                   const float* __restrict__ upart,
                                                   float* __restrict__ out) {
    __shared__ double dred[4];
    __shared__ float Ssh;
    __shared__ float ured[4];
    int tid = threadIdx.x;
    double sl = 0.0;
    #pragma unroll
    for (int i = 0; i < 16; ++i) sl += (double)sfpart[tid + 256 * i];
    #pragma unroll
    for (int o = 32; o >= 1; o >>= 1) sl += __shfl_xor(sl, o);
    if ((tid & 63) == 0) dred[tid >> 6] = sl;
    __syncthreads();
    if (tid == 0) Ssh = (float)(dred[0] + dred[1] + dred[2] + dred[3]);
    __syncthreads();
    float S = Ssh;
    double racc = 0.0;
    #pragma unroll
    for (int i = 0; i < 16; ++i) {
        int b = tid + 256 * i;
        float pred = fm_lin[b] + S + AVG_RATING;
        float d = pred - label[b];
        float rl = d * d;
        out[OUT_PRED + b] = pred;
        out[OUT_RL + b] = rl;
        racc += (double)rl;
    }
    double jacc = 0.0;
    for (int i = tid; i < NW; i += 256) jacc += jpart[i];
    float u = (tid < 32) ? upart[tid] : 0.f;
    #pragma unroll
    for (int o = 32; o >= 1; o >>= 1) {
        racc += __shfl_xor(racc, o);
        jacc += __shfl_xor(jacc, o);
        u    += __shfl_xor(u, o);
    }
    __syncthreads();
    if ((tid & 63) == 0) dred[tid >> 6] = racc;
    __syncthreads();
    double rsum = dred[0] + dred[1] + dred[2] + dred[3];
    __syncthreads();
    if ((tid & 63) == 0) dred[tid >> 6] = jacc;
    __syncthreads();
    double jsum = dred[0] + dred[1] + dred[2] + dred[3];
    if ((tid & 63) == 0) ured[tid >> 6] = u;
    __syncthreads();
    if (tid == 0) {
        double U = (double)(ured[0] + ured[1] + ured[2] + ured[3]) / 1024.0;
        double J = jsum / (2.0 * R_CNT);
        double RL = rsum / (double)B_CNT;
        out[OUT_OBJ] = (float)(RL + U + J);
    }
}

extern "C" void kernel_launch(void* const* d_in, const int* in_sizes, int n_in,
                              void* d_out, int out_size, void* d_ws, size_t ws_size,
                              hipStream_t stream) {
    const float* e_w   = (const float*)d_in[0];
    const float* y_s   = (const float*)d_in[1];
    const float* z_n   = (const float*)d_in[2];
    const float* label = (const float*)d_in[3];
    const float* u_val = (const float*)d_in[4];
    const float* i_val = (const float*)d_in[5];
    const float* M_w   = (const float*)d_in[6];
    const float* W_w   = (const float*)d_in[8];
    const float* W_b   = (const float*)d_in[9];
    const float* T_w   = (const float*)d_in[10];
    const float* T_b   = (const float*)d_in[11];
    const float* fc_w  = (const float*)d_in[12];
    const float* fc_b  = (const float*)d_in[13];
    const float* fm_V  = (const float*)d_in[14];
    const int*   u_idx = (const int*)d_in[15];
    const int*   i_idx = (const int*)d_in[16];

    float* out = (float*)d_out;
    char* ws = (char*)d_ws;
    int* mode     = (int*)(ws + WS_MODE);
    float* fm_lin = (float*)(ws + WS_FMLIN);
    float* p_t    = (float*)(ws + WS_PT);
    float* V      = (float*)(ws + WS_V);
    double* jpart = (double*)(ws + WS_JPART);
    float* sfpart = (float*)(ws + WS_SFPART);
    float* upart  = (float*)(ws + WS_UPART);
    int* cnt      = (int*)(ws + WS_CNT);
    long long* buck = (long long*)(ws + WS_BUCK);

    k_pre<<<346, 256, 0, stream>>>(y_s, M_w, T_w, u_idx, V, upart, cnt, mode);
    k_bucket<<<2 * NNZ_CNT / 256, 256, 0, stream>>>(u_idx, i_idx, u_val, i_val,
                                                    mode, cnt, buck);
    k_zs<<<NW, 64, 0, stream>>>(e_w, V, z_n, W_w, W_b, T_w, T_b, p_t, out, jpart);
    k_rowsum_fm<<<B_CNT, 64, 0, stream>>>(buck, cnt, p_t, fc_w, fc_b, fm_V,
                                          fm_lin, sfpart, out);
    k_predfinal<<<1, 256, 0, stream>>>(label, fm_lin, sfpart, jpart, upart, out);
}